// Round 15
// baseline (246.587 us; speedup 1.0000x reference)
//
#include <hip/hip_runtime.h>

typedef unsigned short u16;
typedef unsigned int u32;
typedef __attribute__((ext_vector_type(8))) __bf16 bf16x8;
typedef __attribute__((ext_vector_type(8))) u16 u16x8;
typedef __attribute__((ext_vector_type(4))) u16 u16x4;
typedef __attribute__((ext_vector_type(4))) float f32x4;
typedef __attribute__((ext_vector_type(2))) u32 u32x2;
typedef __attribute__((ext_vector_type(4))) u32 u32x4;

#define DEV static __device__ __forceinline__

DEV u16 f2bf(float f) {
  unsigned u = __builtin_bit_cast(unsigned, f);
  u += 0x7FFFu + ((u >> 16) & 1u);
  return (u16)(u >> 16);
}

DEV float ex2(float x) { return __builtin_amdgcn_exp2f(x); }

DEV u32 cvt_pk_bf16(float lo, float hi) {
  u32 r;
  asm("v_cvt_pk_bf16_f32 %0, %1, %2" : "=v"(r) : "v"(lo), "v"(hi));
  return r;
}

DEV f32x4 mfma16(bf16x8 a, bf16x8 b, f32x4 c) {
  return __builtin_amdgcn_mfma_f32_16x16x32_bf16(a, b, c, 0, 0, 0);
}

DEV f32x4 fmax4(f32x4 a, f32x4 b) {
  f32x4 r;
  r[0] = fmaxf(a[0], b[0]); r[1] = fmaxf(a[1], b[1]);
  r[2] = fmaxf(a[2], b[2]); r[3] = fmaxf(a[3], b[3]);
  return r;
}

DEV void gload_lds16(const u16* g, u16* lds) {
  __builtin_amdgcn_global_load_lds(
      (const __attribute__((address_space(1))) void*)g,
      (__attribute__((address_space(3))) void*)lds, 16, 0, 0);
}

DEV void vm_wait6() { asm volatile("s_waitcnt vmcnt(6)" ::: "memory"); }
DEV void vm_wait4() { asm volatile("s_waitcnt vmcnt(4)" ::: "memory"); }
DEV void vm_wait2() { asm volatile("s_waitcnt vmcnt(2)" ::: "memory"); }
DEV void vm_wait0() { asm volatile("s_waitcnt vmcnt(0)" ::: "memory"); }
DEV void lgkm_wait0() { asm volatile("s_waitcnt lgkmcnt(0)" ::: "memory"); }

// ---- convert: x, wq, wk, wv -> bf16; bias pack. (wo stays fp32: consumed
// directly by gemm_wo's reg-staged B path.)
__global__ __launch_bounds__(256) void cvt_all(
    const float* __restrict__ x, const float* __restrict__ wq,
    const float* __restrict__ wk, const float* __restrict__ wv,
    const float* __restrict__ qb, const float* __restrict__ kb,
    const float* __restrict__ vb,
    u16* __restrict__ x_bf, u16* __restrict__ wqkv_bf,
    float* __restrict__ bias_p) {
  const int NX = 1536 * 2880 / 4;        // x quads
  const int NWQ = 4096 * 2880 / 4;       // wq quads
  const int NWKV = 512 * 2880 / 4;       // wk / wv quads
  const int C0 = NX, C1 = C0 + NWQ, C2 = C1 + NWKV, C3 = C2 + NWKV;
  const int C4 = C3 + 5120 / 4;
  int i = blockIdx.x * 256 + threadIdx.x;
  if (i >= C4) return;
  if (i < C3) {
    const float* s;
    u16* d;
    if (i < C0) { s = x + (size_t)i * 4; d = x_bf + (size_t)i * 4; }
    else if (i < C1) { size_t q = i - C0; s = wq + q * 4; d = wqkv_bf + q * 4; }
    else if (i < C2) { size_t q = i - C1; s = wk + q * 4; d = wqkv_bf + (size_t)NWQ * 4 + q * 4; }
    else { size_t q = i - C2; s = wv + q * 4; d = wqkv_bf + (size_t)(NWQ + NWKV) * 4 + q * 4; }
    float4 v = *(const float4*)s;
    u16x4 o = {f2bf(v.x), f2bf(v.y), f2bf(v.z), f2bf(v.w)};
    *(u16x4*)d = o;
  } else {
    int e = (i - C3) * 4;
#pragma unroll
    for (int j = 0; j < 4; j++) {
      int idx = e + j;
      bias_p[idx] = (idx < 4096) ? qb[idx] : (idx < 4608 ? kb[idx - 4096] : vb[idx - 4608]);
    }
  }
}

// ---- 128x128 tile GEMM, BK=64, 8 waves (4x2), counted-vmcnt 2-deep pipeline,
// XOR-swizzled LDS, bm-inner XCD-chunked order. grid %8 == 0. (r13-verified)
// MODE 1: QKV epilogue -> Obf[S][5120] bf16 with bias + RoPE(Q,K) + Q-scale.
template <int MODE>
__global__ __launch_bounds__(512) void gemm128(const u16* __restrict__ A,
                                               const u16* __restrict__ B,
                                               const float* __restrict__ bias,
                                               float* __restrict__ C,
                                               u16* __restrict__ Obf,
                                               const float* __restrict__ rope,
                                               int M, int K, int Nreal, int ldc) {
  __shared__ u16 smA[2][128 * 64];
  __shared__ u16 smB[2][128 * 64];
  int nbm = M >> 7;
  int chunk = gridDim.x >> 3;
  int wg = (blockIdx.x & 7) * chunk + (blockIdx.x >> 3);
  int bm = wg % nbm, bn = wg / nbm;
  int t = threadIdx.x, lane = t & 63, wv = t >> 6;
  int wr = wv >> 1, wc = wv & 1;  // 4x2 wave grid; wave tile 32 rows x 64 cols
  int l15 = lane & 15, hi = lane >> 4;
  f32x4 acc[2][4] = {};
  int tr = t >> 3;
  int scol = ((t & 7) ^ (tr & 7)) * 8;
  const u16* Ab = A + (size_t)(bm * 128 + tr) * K + scol;
  const u16* Bb = B + (size_t)(bn * 128 + tr) * K + scol;

  auto stage = [&](int b, int ks) {  // 4 loads / thread
    int k0 = ks * 64;
    gload_lds16(Ab + k0, &smA[b][t * 8]);
    gload_lds16(Ab + k0 + (size_t)64 * K, &smA[b][4096 + t * 8]);
    gload_lds16(Bb + k0, &smB[b][t * 8]);
    gload_lds16(Bb + k0 + (size_t)64 * K, &smB[b][4096 + t * 8]);
  };

  int NK = K >> 6;
  stage(0, 0);
  stage(1, 1);
  for (int ks = 0; ks < NK; ks++) {
    int cur = ks & 1;
    if (ks + 1 < NK) vm_wait4(); else vm_wait0();  // tile ks complete
    __builtin_amdgcn_s_barrier();
    __builtin_amdgcn_sched_barrier(0);
#pragma unroll
    for (int kk = 0; kk < 2; kk++) {
      int sc = ((kk * 4 + hi) ^ (l15 & 7)) * 8;
      bf16x8 af[2], bfr[4];
#pragma unroll
      for (int m = 0; m < 2; m++)
        af[m] = *(const bf16x8*)(&smA[cur][(wr * 32 + m * 16 + l15) * 64 + sc]);
#pragma unroll
      for (int n = 0; n < 4; n++)
        bfr[n] = *(const bf16x8*)(&smB[cur][(wc * 64 + n * 16 + l15) * 64 + sc]);
      __builtin_amdgcn_s_setprio(1);
#pragma unroll
      for (int m = 0; m < 2; m++)
#pragma unroll
        for (int n = 0; n < 4; n++)
          acc[m][n] = mfma16(af[m], bfr[n], acc[m][n]);
      __builtin_amdgcn_s_setprio(0);
    }
    __builtin_amdgcn_s_barrier();        // all waves done reading buf cur
    if (ks + 2 < NK) stage(cur, ks + 2); // refill freed buffer
  }

  int r0 = bm * 128 + wr * 32 + hi * 4;
  int c0 = bn * 128 + wc * 64 + l15;
  if (MODE == 0) {
#pragma unroll
    for (int n = 0; n < 4; n++) {
      int col = c0 + n * 16;
      if (col >= Nreal) continue;
      float bv = bias[col];
#pragma unroll
      for (int m = 0; m < 2; m++)
#pragma unroll
        for (int r = 0; r < 4; r++)
          C[(size_t)(r0 + m * 16 + r) * ldc + col] = acc[m][n][r] + bv;
    }
  } else {
    float bv[4];
#pragma unroll
    for (int n = 0; n < 4; n++) bv[n] = bias[c0 + n * 16];
    if (bn < 36) {  // Q or K head: RoPE (head = 64 cols = one wave tile)
      float scale = (bn < 32) ? 0.180336880f : 1.0f;  // Q: 0.125*log2(e)
#pragma unroll
      for (int m = 0; m < 2; m++) {
#pragma unroll
        for (int r = 0; r < 4; r++) {
          int s = r0 + m * 16 + r;
          const float* rp = rope + (size_t)s * 128;
          float cv0 = rp[l15], cv1 = rp[l15 + 16];
          float sv0 = rp[64 + l15], sv1 = rp[64 + l15 + 16];
          float v0 = acc[0][0][r], v1 = acc[0][1][r];
          float v2 = acc[0][2][r], v3 = acc[0][3][r];
          if (m) { v0 = acc[1][0][r]; v1 = acc[1][1][r]; v2 = acc[1][2][r]; v3 = acc[1][3][r]; }
          v0 += bv[0]; v1 += bv[1]; v2 += bv[2]; v3 += bv[3];
          u16* po = Obf + (size_t)s * 5120 + c0;
          po[0]  = f2bf((v0 * cv0 - v2 * sv0) * scale);
          po[16] = f2bf((v1 * cv1 - v3 * sv1) * scale);
          po[32] = f2bf((v2 * cv0 + v0 * sv0) * scale);
          po[48] = f2bf((v3 * cv1 + v1 * sv1) * scale);
        }
      }
    } else {  // V: plain bias + cast
#pragma unroll
      for (int m = 0; m < 2; m++)
#pragma unroll
        for (int r = 0; r < 4; r++) {
          int s = r0 + m * 16 + r;
          u16* po = Obf + (size_t)s * 5120 + c0;
#pragma unroll
          for (int n = 0; n < 4; n++) po[n * 16] = f2bf(acc[m][n][r] + bv[n]);
        }
    }
  }
}

// ---- wo projection GEMM: B read DIRECTLY from fp32 (no conversion pass).
// Same r13 skeleton (128x128, 8 waves 4x2, 2-deep), but B is reg-staged:
// 4x float4 fp32 loads -> cvt_pk -> 2x ds_write_b128 into the swizzled slots.
// Named even/odd reg sets (no runtime-indexed arrays), NK even (K=4096).
// Rows >= Brows are zero-filled in registers (replaces the pad buffer).
__global__ __launch_bounds__(512) void gemm_wo(const u16* __restrict__ A,
                                               const float* __restrict__ Bf,
                                               const float* __restrict__ bias,
                                               float* __restrict__ C,
                                               int M, int K, int Nreal, int ldc,
                                               int Brows) {
  __shared__ u16 smA[2][128 * 64];
  __shared__ u16 smB[2][128 * 64];
  int nbm = M >> 7;
  int chunk = gridDim.x >> 3;
  int wg = (blockIdx.x & 7) * chunk + (blockIdx.x >> 3);
  int bm = wg % nbm, bn = wg / nbm;
  int t = threadIdx.x, lane = t & 63, wv = t >> 6;
  int wr = wv >> 1, wc = wv & 1;
  int l15 = lane & 15, hi = lane >> 4;
  f32x4 acc[2][4] = {};
  int tr = t >> 3;
  int scol = ((t & 7) ^ (tr & 7)) * 8;  // (tr+64)&7 == tr&7: same swizzle both halves
  const u16* Ab = A + (size_t)(bm * 128 + tr) * K + scol;
  int brow0 = bn * 128 + tr, brow1 = brow0 + 64;
  bool b0ok = brow0 < Brows, b1ok = brow1 < Brows;
  const float* Bp0 = Bf + (size_t)(b0ok ? brow0 : 0) * K + scol;
  const float* Bp1 = Bf + (size_t)(b1ok ? brow1 : 0) * K + scol;
  const float4 z4 = {0.f, 0.f, 0.f, 0.f};

  float4 e0, e1, e2, e3;  // even-stage B regs
  float4 o0, o1, o2, o3;  // odd-stage B regs

  auto stageA = [&](int b, int ks) {  // 2 gload_lds / thread
    int k0 = ks * 64;
    gload_lds16(Ab + k0, &smA[b][t * 8]);
    gload_lds16(Ab + k0 + (size_t)64 * K, &smA[b][4096 + t * 8]);
  };

#define BLOAD(r0, r1, r2, r3, ks)                                   \
  do {                                                              \
    int k0 = (ks) * 64;                                             \
    r0 = *(const float4*)(Bp0 + k0);                                \
    r1 = *(const float4*)(Bp0 + k0 + 4);                            \
    r2 = *(const float4*)(Bp1 + k0);                                \
    r3 = *(const float4*)(Bp1 + k0 + 4);                            \
    if (!b0ok) { r0 = z4; r1 = z4; }                                \
    if (!b1ok) { r2 = z4; r3 = z4; }                                \
  } while (0)

#define BWRITE(buf, r0, r1, r2, r3)                                 \
  do {                                                              \
    u32x4 lo = {cvt_pk_bf16(r0.x, r0.y), cvt_pk_bf16(r0.z, r0.w),   \
                cvt_pk_bf16(r1.x, r1.y), cvt_pk_bf16(r1.z, r1.w)};  \
    *(u32x4*)(&smB[buf][t * 8]) = lo;                               \
    u32x4 hi4 = {cvt_pk_bf16(r2.x, r2.y), cvt_pk_bf16(r2.z, r2.w),  \
                 cvt_pk_bf16(r3.x, r3.y), cvt_pk_bf16(r3.z, r3.w)}; \
    *(u32x4*)(&smB[buf][4096 + t * 8]) = hi4;                       \
  } while (0)

  auto compute = [&](int cur) {
#pragma unroll
    for (int kk = 0; kk < 2; kk++) {
      int sc = ((kk * 4 + hi) ^ (l15 & 7)) * 8;
      bf16x8 af[2], bfr[4];
#pragma unroll
      for (int m = 0; m < 2; m++)
        af[m] = *(const bf16x8*)(&smA[cur][(wr * 32 + m * 16 + l15) * 64 + sc]);
#pragma unroll
      for (int n = 0; n < 4; n++)
        bfr[n] = *(const bf16x8*)(&smB[cur][(wc * 64 + n * 16 + l15) * 64 + sc]);
      __builtin_amdgcn_s_setprio(1);
#pragma unroll
      for (int m = 0; m < 2; m++)
#pragma unroll
        for (int n = 0; n < 4; n++)
          acc[m][n] = mfma16(af[m], bfr[n], acc[m][n]);
      __builtin_amdgcn_s_setprio(0);
    }
  };

  const int NK = K >> 6;  // 64 (even)
  stageA(0, 0); BLOAD(e0, e1, e2, e3, 0);
  stageA(1, 1); BLOAD(o0, o1, o2, o3, 1);
  for (int ks = 0; ks < NK; ks += 2) {
    // --- even half: tile ks in buf 0
    if (ks + 1 < NK) vm_wait6(); else vm_wait0();  // A[ks] in LDS
    BWRITE(0, e0, e1, e2, e3);                      // B[ks] (compiler waits regs)
    lgkm_wait0();                                   // own ds_writes done
    __builtin_amdgcn_s_barrier();
    __builtin_amdgcn_sched_barrier(0);
    compute(0);
    __builtin_amdgcn_s_barrier();
    if (ks + 2 < NK) { stageA(0, ks + 2); BLOAD(e0, e1, e2, e3, ks + 2); }
    // --- odd half: tile ks+1 in buf 1
    if (ks + 2 < NK) vm_wait6(); else vm_wait0();
    BWRITE(1, o0, o1, o2, o3);
    lgkm_wait0();
    __builtin_amdgcn_s_barrier();
    __builtin_amdgcn_sched_barrier(0);
    compute(1);
    __builtin_amdgcn_s_barrier();
    if (ks + 3 < NK) { stageA(1, ks + 3); BLOAD(o0, o1, o2, o3, ks + 3); }
  }
#undef BLOAD
#undef BWRITE

  int r0 = bm * 128 + wr * 32 + hi * 4;
  int c0 = bn * 128 + wc * 64 + l15;
#pragma unroll
  for (int n = 0; n < 4; n++) {
    int col = c0 + n * 16;
    if (col >= Nreal) continue;
    float bv = bias[col];
#pragma unroll
    for (int m = 0; m < 2; m++)
#pragma unroll
      for (int r = 0; r < 4; r++)
        C[(size_t)(r0 + m * 16 + r) * ldc + col] = acc[m][n][r] + bv;
  }
}

// ---- V transpose: src [S][ld] bf16 (cols col0+) -> dst [Hkv][64][S] bf16
__global__ __launch_bounds__(256) void cast_trT(const u16* __restrict__ src,
                                                u16* __restrict__ dst, int S, int Hkv,
                                                int ld, int col0) {
  __shared__ u16 tile[64][65];
  int s0 = blockIdx.x * 64;
  int hkv = blockIdx.y;
  int t = threadIdx.x;
  int dl = (t & 15) * 4;
  int sl = t >> 4;
#pragma unroll
  for (int j = 0; j < 4; j++) {
    int s = sl + j * 16;
    u16x4 v = *(const u16x4*)(src + (size_t)(s0 + s) * ld + col0 + hkv * 64 + dl);
    tile[dl + 0][s] = v[0];
    tile[dl + 1][s] = v[1];
    tile[dl + 2][s] = v[2];
    tile[dl + 3][s] = v[3];
  }
  __syncthreads();
  int sl2 = (t & 7) * 8;
  int dl2 = t >> 3;
#pragma unroll
  for (int j = 0; j < 2; j++) {
    int d = dl2 + j * 32;
    u16x8 o;
#pragma unroll
    for (int c = 0; c < 8; c++) o[c] = tile[d][sl2 + c];
    *(u16x8*)(dst + ((size_t)hkv * 64 + d) * S + s0 + sl2) = o;
  }
}

// ---- flash attention fwd: block = 8 waves (512 thr), TWO heads sharing one
// hkv group (waves 0-3 -> head 2*pair, waves 4-7 -> head 2*pair+1; K/V tiles
// staged once, used by both), and TWO sequential q-tile passes for uniform
// work: qbA = 12+bx (long) then qbB = 11-bx (short). (r13-verified)
__global__ __launch_bounds__(512) void attn_fwd(const u16* __restrict__ QKV,
                                                const u16* __restrict__ VT,
                                                const float* __restrict__ sinks,
                                                u16* __restrict__ Out,
                                                int S, int H, int Hkv) {
  __shared__ u16 ldsK[2][64 * 64];
  __shared__ u16 ldsV[2][64 * 64];  // V^T tile: [d][k]
  __shared__ u16 ldsP[8][16 * 64];
  int bx = blockIdx.x, pair = blockIdx.y;
  int t = threadIdx.x, lane = t & 63, wv = t >> 6;
  int wq = wv & 3;                // q-tile slice within pass
  int h = pair * 2 + (wv >> 2);   // this wave's head
  int hkv = pair >> 2;            // shared by both heads of the pair
  int l15 = lane & 15, hi = lane >> 4;
  const u16* Kh = QKV + 4096 + hkv * 64;
  const u16* VTh = VT + (size_t)hkv * 64 * S;
  u16* ldsPw = &ldsP[wv][0];
  int psw = (l15 & 7) << 4;  // P swizzle for this lane's row
  float snk = sinks[h];

  auto stage = [&](int b, int kb) {  // 2 loads / thread (512 thr = full tiles)
    int k0 = kb * 64;
    int row = t >> 3, c16 = t & 7;
    int sc = (c16 ^ (row & 7)) * 8;
    gload_lds16(Kh + (size_t)(k0 + row) * 5120 + sc, &ldsK[b][t * 8]);
    gload_lds16(VTh + (size_t)row * S + k0 + sc, &ldsV[b][t * 8]);
  };

  for (int pass = 0; pass < 2; pass++) {
    int qb = pass == 0 ? (12 + bx) : (11 - bx);
    int q0 = qb * 64 + wq * 16;
    int rowq = q0 + l15;
    const u16* Qh = QKV + (size_t)q0 * 5120 + h * 64;
    bf16x8 qf[2];
    qf[0] = *(const bf16x8*)(Qh + (size_t)l15 * 5120 + hi * 8);
    qf[1] = *(const bf16x8*)(Qh + (size_t)l15 * 5120 + 32 + hi * 8);

    float mx = -1e30f, ls = 0.f;  // per-lane state for q-row (q0 + l15), log2
    f32x4 ao[4] = {};

    int nkb = qb + 1;
    stage(0, 0);
    if (nkb > 1) stage(1, 1);
    for (int kb = 0; kb < nkb; kb++) {
      int cur = kb & 1;
      if (kb + 1 < nkb) vm_wait2(); else vm_wait0();  // tile kb complete
      __builtin_amdgcn_s_barrier();
      __builtin_amdgcn_sched_barrier(0);
      {
        // QK^T swapped: s[ct][r] = score(q=q0+l15, k=kb*64+ct*16+hi*4+r)
        f32x4 s[4] = {};
        __builtin_amdgcn_s_setprio(1);
#pragma unroll
        for (int kk = 0; kk < 2; kk++) {
#pragma unroll
          for (int ct = 0; ct < 4; ct++) {
            int row = ct * 16 + l15;
            int c16 = (kk * 4 + hi) ^ (row & 7);
            bf16x8 kf = *(const bf16x8*)(&ldsK[cur][row * 64 + c16 * 8]);
            s[ct] = mfma16(kf, qf[kk], s[ct]);
          }
        }
        __builtin_amdgcn_s_setprio(0);

        bool full = (kb * 64 + 63) < q0;  // wave-uniform: tile unmasked
        if (!full) {
          int kc = kb * 64 + hi * 4;
#pragma unroll
          for (int ct = 0; ct < 4; ct++)
#pragma unroll
            for (int r = 0; r < 4; r++)
              if (kc + ct * 16 + r > rowq) s[ct][r] = -1e30f;
        }

        // row max: in-register tree + 2 shuffles across the 4 hi-replicas
        f32x4 mm = fmax4(fmax4(s[0], s[1]), fmax4(s[2], s[3]));
        float tmx = fmaxf(fmaxf(mm[0], mm[1]), fmaxf(mm[2], mm[3]));
        tmx = fmaxf(tmx, __shfl_xor(tmx, 16));
        tmx = fmaxf(tmx, __shfl_xor(tmx, 32));
        bool upd = __any(tmx > mx + 8.0f);  // defer-max
        if (upd) {
          float mn = fmaxf(mx, tmx);
          float al = ex2(mx - mn);
          mx = mn;
          ls *= al;
          float alr[4];
#pragma unroll
          for (int r = 0; r < 4; r++) alr[r] = __shfl(al, hi * 4 + r);
#pragma unroll
          for (int nt = 0; nt < 4; nt++)
#pragma unroll
            for (int r = 0; r < 4; r++) ao[nt][r] *= alr[r];
        }
#pragma unroll
        for (int ct = 0; ct < 4; ct++)
#pragma unroll
          for (int r = 0; r < 4; r++) s[ct][r] = ex2(s[ct][r] - mx);
        f32x4 sm = s[0] + s[1] + s[2] + s[3];
        float rs = (sm[0] + sm[1]) + (sm[2] + sm[3]);
        rs += __shfl_xor(rs, 16);
        rs += __shfl_xor(rs, 32);
        ls += rs;

        // P -> per-wave LDS (row l15, XOR-swizzled, 8B writes)
#pragma unroll
        for (int ct = 0; ct < 4; ct++) {
          u32x2 pk = {cvt_pk_bf16(s[ct][0], s[ct][1]),
                      cvt_pk_bf16(s[ct][2], s[ct][3])};
          *(u32x2*)(&ldsPw[(l15 * 128 + ((ct * 32 + hi * 8) ^ psw)) >> 1]) = pk;
        }

        // PV (per-wave ldsP: no barrier, same-wave DS ordering)
        __builtin_amdgcn_s_setprio(1);
#pragma unroll
        for (int kk = 0; kk < 2; kk++) {
          bf16x8 pa = *(const bf16x8*)(&ldsPw[(l15 * 128 + ((kk * 64 + hi * 16) ^ psw)) >> 1]);
#pragma unroll
          for (int nt = 0; nt < 4; nt++) {
            int vrow = nt * 16 + l15;
            int c16 = (kk * 4 + hi) ^ (vrow & 7);
            bf16x8 vf = *(const bf16x8*)(&ldsV[cur][vrow * 64 + c16 * 8]);
            ao[nt] = mfma16(pa, vf, ao[nt]);
          }
        }
        __builtin_amdgcn_s_setprio(0);
      }
      __builtin_amdgcn_s_barrier();          // all waves done with buf cur
      if (kb + 2 < nkb) stage(cur, kb + 2);  // refill freed buffer
    }

    float lse = 0.69314718056f * mx + __logf(ls);  // back to natural log
    float ss = 1.f / (1.f + __expf(snk - lse));
    float f = ss / ls;
    float fr[4];
#pragma unroll
    for (int r = 0; r < 4; r++) fr[r] = __shfl(f, hi * 4 + r);
#pragma unroll
    for (int r = 0; r < 4; r++) {
      int row = q0 + hi * 4 + r;
#pragma unroll
      for (int nt = 0; nt < 4; nt++)
        Out[(size_t)row * (H * 64) + h * 64 + nt * 16 + l15] = f2bf(ao[nt][r] * fr[r]);
    }
  }
}

extern "C" void kernel_launch(void* const* d_in, const int* in_sizes, int n_in,
                              void* d_out, int out_size, void* d_ws, size_t ws_size,
                              hipStream_t stream) {
  const int S = 1536, HID = 2880, H = 64, HKV = 8;
  const int NQ = 4096, NKV = 512, NQKV = 5120, NPAD = 3072;

  const float* x     = (const float*)d_in[0];
  const float* rope  = (const float*)d_in[1];
  const float* wq_w  = (const float*)d_in[2];
  const float* wq_b  = (const float*)d_in[3];
  const float* wk_w  = (const float*)d_in[4];
  const float* wk_b  = (const float*)d_in[5];
  const float* wv_w  = (const float*)d_in[6];
  const float* wv_b  = (const float*)d_in[7];
  const float* wo_w  = (const float*)d_in[8];
  const float* wo_b  = (const float*)d_in[9];
  const float* sinks = (const float*)d_in[10];
  float* out = (float*)d_out;

  char* ws = (char*)d_ws;
  size_t off = 0;
  auto alloc = [&](size_t bytes) {
    char* p = ws + off;
    off = (off + bytes + 255) & ~(size_t)255;
    return p;
  };
  u16*   x_bf    = (u16*)  alloc((size_t)S * HID * 2);
  u16*   wqkv_bf = (u16*)  alloc((size_t)NQKV * HID * 2);
  u16*   qkv_bf  = (u16*)  alloc((size_t)S * NQKV * 2);
  float* bias_p  = (float*)alloc((size_t)NQKV * 4);
  u16*   VTb     = (u16*)  alloc((size_t)HKV * 64 * S * 2);
  u16*   att     = (u16*)  alloc((size_t)S * NQ * 2);
  (void)ws_size; (void)n_in; (void)in_sizes; (void)out_size;

  auto cdiv = [](int a, int b) { return (a + b - 1) / b; };

  const int NCVT = S * HID / 4 + NQ * HID / 4 + 2 * (NKV * HID / 4) + NQKV / 4;
  cvt_all<<<cdiv(NCVT, 256), 256, 0, stream>>>(x, wq_w, wk_w, wv_w,
                                               wq_b, wk_b, wv_b,
                                               x_bf, wqkv_bf, bias_p);

  // QKV projection + bias + RoPE + bf16 epilogue: grid 12 * 40 = 480 (%8==0)
  gemm128<1><<<(S / 128) * (NQKV / 128), 512, 0, stream>>>(
      x_bf, wqkv_bf, bias_p, nullptr, qkv_bf, rope, S, HID, NQKV, NQKV);

  cast_trT<<<dim3(S / 64, HKV), 256, 0, stream>>>(qkv_bf, VTb, S, HKV, NQKV, NQ + NKV);

  // 12 balanced q-pass pairs x 32 head-pairs = 384 uniform blocks
  attn_fwd<<<dim3(12, H / 2), 512, 0, stream>>>(qkv_bf, VTb, sinks, att, S, H, HKV);

  // wo projection, B direct from fp32: grid 12 * 24 = 288 (%8==0)
  gemm_wo<<<(S / 128) * (NPAD / 128), 512, 0, stream>>>(
      att, wo_w, wo_b, out, S, NQ, HID, HID, HID);
}

// Round 16
// 186.544 us; speedup vs baseline: 1.3219x; 1.3219x over previous
//
#include <hip/hip_runtime.h>

typedef unsigned short u16;
typedef unsigned int u32;
typedef __attribute__((ext_vector_type(8))) __bf16 bf16x8;
typedef __attribute__((ext_vector_type(8))) u16 u16x8;
typedef __attribute__((ext_vector_type(4))) u16 u16x4;
typedef __attribute__((ext_vector_type(4))) float f32x4;
typedef __attribute__((ext_vector_type(2))) u32 u32x2;

#define DEV static __device__ __forceinline__

DEV u16 f2bf(float f) {
  unsigned u = __builtin_bit_cast(unsigned, f);
  u += 0x7FFFu + ((u >> 16) & 1u);
  return (u16)(u >> 16);
}

DEV float ex2(float x) { return __builtin_amdgcn_exp2f(x); }

DEV u32 cvt_pk_bf16(float lo, float hi) {
  u32 r;
  asm("v_cvt_pk_bf16_f32 %0, %1, %2" : "=v"(r) : "v"(lo), "v"(hi));
  return r;
}

DEV f32x4 mfma16(bf16x8 a, bf16x8 b, f32x4 c) {
  return __builtin_amdgcn_mfma_f32_16x16x32_bf16(a, b, c, 0, 0, 0);
}

DEV f32x4 fmax4(f32x4 a, f32x4 b) {
  f32x4 r;
  r[0] = fmaxf(a[0], b[0]); r[1] = fmaxf(a[1], b[1]);
  r[2] = fmaxf(a[2], b[2]); r[3] = fmaxf(a[3], b[3]);
  return r;
}

DEV void gload_lds16(const u16* g, u16* lds) {
  __builtin_amdgcn_global_load_lds(
      (const __attribute__((address_space(1))) void*)g,
      (__attribute__((address_space(3))) void*)lds, 16, 0, 0);
}

DEV void vm_wait4() { asm volatile("s_waitcnt vmcnt(4)" ::: "memory"); }
DEV void vm_wait2() { asm volatile("s_waitcnt vmcnt(2)" ::: "memory"); }
DEV void vm_wait0() { asm volatile("s_waitcnt vmcnt(0)" ::: "memory"); }

// ---- one-shot convert, 8 elems/thread: x, wq, wk, wv -> bf16; wo -> bf16
// padded to 3072 rows; bias pack. All section sizes % 8 == 0; wo rows are
// 4096 wide so 8-chunks never straddle the pad boundary.
__global__ __launch_bounds__(256) void cvt_all(
    const float* __restrict__ x, const float* __restrict__ wq,
    const float* __restrict__ wk, const float* __restrict__ wv,
    const float* __restrict__ wo, const float* __restrict__ qb,
    const float* __restrict__ kb, const float* __restrict__ vb,
    u16* __restrict__ x_bf, u16* __restrict__ wqkv_bf,
    u16* __restrict__ wo_bf, float* __restrict__ bias_p) {
  const int NX = 1536 * 2880 / 8;        // x octs
  const int NWQ = 4096 * 2880 / 8;       // wq octs
  const int NWKV = 512 * 2880 / 8;       // wk / wv octs
  const int NWO = 3072 * 4096 / 8;       // wo padded octs
  const int C0 = NX, C1 = C0 + NWQ, C2 = C1 + NWKV, C3 = C2 + NWKV;
  const int C4 = C3 + NWO, C5 = C4 + 5120 / 8;
  int i = blockIdx.x * 256 + threadIdx.x;
  if (i >= C5) return;
  if (i < C4) {
    const float* s;
    u16* d;
    bool pad = false;
    if (i < C0) { s = x + (size_t)i * 8; d = x_bf + (size_t)i * 8; }
    else if (i < C1) { size_t q = i - C0; s = wq + q * 8; d = wqkv_bf + q * 8; }
    else if (i < C2) { size_t q = i - C1; s = wk + q * 8; d = wqkv_bf + (size_t)NWQ * 8 + q * 8; }
    else if (i < C3) { size_t q = i - C2; s = wv + q * 8; d = wqkv_bf + (size_t)(NWQ + NWKV) * 8 + q * 8; }
    else {
      size_t q = i - C3;
      int row = (int)(q >> 9);  // 4096/8 = 512 octs per row
      pad = (row >= 2880);
      s = wo + q * 8; d = wo_bf + q * 8;
    }
    u16x8 o;
    if (!pad) {
      float4 v0 = *(const float4*)s;
      float4 v1 = *(const float4*)(s + 4);
      o = (u16x8){f2bf(v0.x), f2bf(v0.y), f2bf(v0.z), f2bf(v0.w),
                  f2bf(v1.x), f2bf(v1.y), f2bf(v1.z), f2bf(v1.w)};
    } else {
      o = (u16x8){0, 0, 0, 0, 0, 0, 0, 0};
    }
    *(u16x8*)d = o;
  } else {
    int e = (i - C4) * 8;
#pragma unroll
    for (int j = 0; j < 8; j++) {
      int idx = e + j;
      bias_p[idx] = (idx < 4096) ? qb[idx] : (idx < 4608 ? kb[idx - 4096] : vb[idx - 4608]);
    }
  }
}

// ---- 128x128 tile GEMM, BK=64, 8 waves (4x2), counted-vmcnt 2-deep pipeline,
// XOR-swizzled LDS, bm-inner XCD-chunked order. grid %8 == 0. (r13-verified)
// MODE 0: C fp32 = A*B^T + bias (cols < Nreal).
// MODE 1: QKV epilogue -> Obf[S][5120] bf16 with bias + RoPE(Q,K) + Q-scale.
template <int MODE>
__global__ __launch_bounds__(512) void gemm128(const u16* __restrict__ A,
                                               const u16* __restrict__ B,
                                               const float* __restrict__ bias,
                                               float* __restrict__ C,
                                               u16* __restrict__ Obf,
                                               const float* __restrict__ rope,
                                               int M, int K, int Nreal, int ldc) {
  __shared__ u16 smA[2][128 * 64];
  __shared__ u16 smB[2][128 * 64];
  int nbm = M >> 7;
  int chunk = gridDim.x >> 3;
  int wg = (blockIdx.x & 7) * chunk + (blockIdx.x >> 3);
  int bm = wg % nbm, bn = wg / nbm;
  int t = threadIdx.x, lane = t & 63, wv = t >> 6;
  int wr = wv >> 1, wc = wv & 1;  // 4x2 wave grid; wave tile 32 rows x 64 cols
  int l15 = lane & 15, hi = lane >> 4;
  f32x4 acc[2][4] = {};
  int tr = t >> 3;
  int scol = ((t & 7) ^ (tr & 7)) * 8;
  const u16* Ab = A + (size_t)(bm * 128 + tr) * K + scol;
  const u16* Bb = B + (size_t)(bn * 128 + tr) * K + scol;

  auto stage = [&](int b, int ks) {  // 4 loads / thread
    int k0 = ks * 64;
    gload_lds16(Ab + k0, &smA[b][t * 8]);
    gload_lds16(Ab + k0 + (size_t)64 * K, &smA[b][4096 + t * 8]);
    gload_lds16(Bb + k0, &smB[b][t * 8]);
    gload_lds16(Bb + k0 + (size_t)64 * K, &smB[b][4096 + t * 8]);
  };

  int NK = K >> 6;
  stage(0, 0);
  stage(1, 1);
  for (int ks = 0; ks < NK; ks++) {
    int cur = ks & 1;
    if (ks + 1 < NK) vm_wait4(); else vm_wait0();  // tile ks complete
    __builtin_amdgcn_s_barrier();
    __builtin_amdgcn_sched_barrier(0);
#pragma unroll
    for (int kk = 0; kk < 2; kk++) {
      int sc = ((kk * 4 + hi) ^ (l15 & 7)) * 8;
      bf16x8 af[2], bfr[4];
#pragma unroll
      for (int m = 0; m < 2; m++)
        af[m] = *(const bf16x8*)(&smA[cur][(wr * 32 + m * 16 + l15) * 64 + sc]);
#pragma unroll
      for (int n = 0; n < 4; n++)
        bfr[n] = *(const bf16x8*)(&smB[cur][(wc * 64 + n * 16 + l15) * 64 + sc]);
      __builtin_amdgcn_s_setprio(1);
#pragma unroll
      for (int m = 0; m < 2; m++)
#pragma unroll
        for (int n = 0; n < 4; n++)
          acc[m][n] = mfma16(af[m], bfr[n], acc[m][n]);
      __builtin_amdgcn_s_setprio(0);
    }
    __builtin_amdgcn_s_barrier();        // all waves done reading buf cur
    if (ks + 2 < NK) stage(cur, ks + 2); // refill freed buffer
  }

  int r0 = bm * 128 + wr * 32 + hi * 4;
  int c0 = bn * 128 + wc * 64 + l15;
  if (MODE == 0) {
#pragma unroll
    for (int n = 0; n < 4; n++) {
      int col = c0 + n * 16;
      if (col >= Nreal) continue;
      float bv = bias[col];
#pragma unroll
      for (int m = 0; m < 2; m++)
#pragma unroll
        for (int r = 0; r < 4; r++)
          C[(size_t)(r0 + m * 16 + r) * ldc + col] = acc[m][n][r] + bv;
    }
  } else {
    float bv[4];
#pragma unroll
    for (int n = 0; n < 4; n++) bv[n] = bias[c0 + n * 16];
    if (bn < 36) {  // Q or K head: RoPE (head = 64 cols = one wave tile)
      float scale = (bn < 32) ? 0.180336880f : 1.0f;  // Q: 0.125*log2(e)
#pragma unroll
      for (int m = 0; m < 2; m++) {
#pragma unroll
        for (int r = 0; r < 4; r++) {
          int s = r0 + m * 16 + r;
          const float* rp = rope + (size_t)s * 128;
          float cv0 = rp[l15], cv1 = rp[l15 + 16];
          float sv0 = rp[64 + l15], sv1 = rp[64 + l15 + 16];
          float v0 = acc[0][0][r], v1 = acc[0][1][r];
          float v2 = acc[0][2][r], v3 = acc[0][3][r];
          if (m) { v0 = acc[1][0][r]; v1 = acc[1][1][r]; v2 = acc[1][2][r]; v3 = acc[1][3][r]; }
          v0 += bv[0]; v1 += bv[1]; v2 += bv[2]; v3 += bv[3];
          u16* po = Obf + (size_t)s * 5120 + c0;
          po[0]  = f2bf((v0 * cv0 - v2 * sv0) * scale);
          po[16] = f2bf((v1 * cv1 - v3 * sv1) * scale);
          po[32] = f2bf((v2 * cv0 + v0 * sv0) * scale);
          po[48] = f2bf((v3 * cv1 + v1 * sv1) * scale);
        }
      }
    } else {  // V: plain bias + cast
#pragma unroll
      for (int m = 0; m < 2; m++)
#pragma unroll
        for (int r = 0; r < 4; r++) {
          int s = r0 + m * 16 + r;
          u16* po = Obf + (size_t)s * 5120 + c0;
#pragma unroll
          for (int n = 0; n < 4; n++) po[n * 16] = f2bf(acc[m][n][r] + bv[n]);
        }
    }
  }
}

// ---- V transpose: src [S][ld] bf16 (cols col0+) -> dst [Hkv][64][S] bf16
__global__ __launch_bounds__(256) void cast_trT(const u16* __restrict__ src,
                                                u16* __restrict__ dst, int S, int Hkv,
                                                int ld, int col0) {
  __shared__ u16 tile[64][65];
  int s0 = blockIdx.x * 64;
  int hkv = blockIdx.y;
  int t = threadIdx.x;
  int dl = (t & 15) * 4;
  int sl = t >> 4;
#pragma unroll
  for (int j = 0; j < 4; j++) {
    int s = sl + j * 16;
    u16x4 v = *(const u16x4*)(src + (size_t)(s0 + s) * ld + col0 + hkv * 64 + dl);
    tile[dl + 0][s] = v[0];
    tile[dl + 1][s] = v[1];
    tile[dl + 2][s] = v[2];
    tile[dl + 3][s] = v[3];
  }
  __syncthreads();
  int sl2 = (t & 7) * 8;
  int dl2 = t >> 3;
#pragma unroll
  for (int j = 0; j < 2; j++) {
    int d = dl2 + j * 32;
    u16x8 o;
#pragma unroll
    for (int c = 0; c < 8; c++) o[c] = tile[d][sl2 + c];
    *(u16x8*)(dst + ((size_t)hkv * 64 + d) * S + s0 + sl2) = o;
  }
}

// ---- flash attention fwd: block = 8 waves (512 thr), TWO heads sharing one
// hkv group (waves 0-3 -> head 2*pair, waves 4-7 -> head 2*pair+1; K/V tiles
// staged once, used by both), and TWO sequential q-tile passes for uniform
// work: qbA = 12+bx (long) then qbB = 11-bx (short). (r13-verified)
__global__ __launch_bounds__(512) void attn_fwd(const u16* __restrict__ QKV,
                                                const u16* __restrict__ VT,
                                                const float* __restrict__ sinks,
                                                u16* __restrict__ Out,
                                                int S, int H, int Hkv) {
  __shared__ u16 ldsK[2][64 * 64];
  __shared__ u16 ldsV[2][64 * 64];  // V^T tile: [d][k]
  __shared__ u16 ldsP[8][16 * 64];
  int bx = blockIdx.x, pair = blockIdx.y;
  int t = threadIdx.x, lane = t & 63, wv = t >> 6;
  int wq = wv & 3;                // q-tile slice within pass
  int h = pair * 2 + (wv >> 2);   // this wave's head
  int hkv = pair >> 2;            // shared by both heads of the pair
  int l15 = lane & 15, hi = lane >> 4;
  const u16* Kh = QKV + 4096 + hkv * 64;
  const u16* VTh = VT + (size_t)hkv * 64 * S;
  u16* ldsPw = &ldsP[wv][0];
  int psw = (l15 & 7) << 4;  // P swizzle for this lane's row
  float snk = sinks[h];

  auto stage = [&](int b, int kb) {  // 2 loads / thread (512 thr = full tiles)
    int k0 = kb * 64;
    int row = t >> 3, c16 = t & 7;
    int sc = (c16 ^ (row & 7)) * 8;
    gload_lds16(Kh + (size_t)(k0 + row) * 5120 + sc, &ldsK[b][t * 8]);
    gload_lds16(VTh + (size_t)row * S + k0 + sc, &ldsV[b][t * 8]);
  };

  for (int pass = 0; pass < 2; pass++) {
    int qb = pass == 0 ? (12 + bx) : (11 - bx);
    int q0 = qb * 64 + wq * 16;
    int rowq = q0 + l15;
    const u16* Qh = QKV + (size_t)q0 * 5120 + h * 64;
    bf16x8 qf[2];
    qf[0] = *(const bf16x8*)(Qh + (size_t)l15 * 5120 + hi * 8);
    qf[1] = *(const bf16x8*)(Qh + (size_t)l15 * 5120 + 32 + hi * 8);

    float mx = -1e30f, ls = 0.f;  // per-lane state for q-row (q0 + l15), log2
    f32x4 ao[4] = {};

    int nkb = qb + 1;
    stage(0, 0);
    if (nkb > 1) stage(1, 1);
    for (int kb = 0; kb < nkb; kb++) {
      int cur = kb & 1;
      if (kb + 1 < nkb) vm_wait2(); else vm_wait0();  // tile kb complete
      __builtin_amdgcn_s_barrier();
      __builtin_amdgcn_sched_barrier(0);
      {
        // QK^T swapped: s[ct][r] = score(q=q0+l15, k=kb*64+ct*16+hi*4+r)
        f32x4 s[4] = {};
        __builtin_amdgcn_s_setprio(1);
#pragma unroll
        for (int kk = 0; kk < 2; kk++) {
#pragma unroll
          for (int ct = 0; ct < 4; ct++) {
            int row = ct * 16 + l15;
            int c16 = (kk * 4 + hi) ^ (row & 7);
            bf16x8 kf = *(const bf16x8*)(&ldsK[cur][row * 64 + c16 * 8]);
            s[ct] = mfma16(kf, qf[kk], s[ct]);
          }
        }
        __builtin_amdgcn_s_setprio(0);

        bool full = (kb * 64 + 63) < q0;  // wave-uniform: tile unmasked
        if (!full) {
          int kc = kb * 64 + hi * 4;
#pragma unroll
          for (int ct = 0; ct < 4; ct++)
#pragma unroll
            for (int r = 0; r < 4; r++)
              if (kc + ct * 16 + r > rowq) s[ct][r] = -1e30f;
        }

        // row max: in-register tree + 2 shuffles across the 4 hi-replicas
        f32x4 mm = fmax4(fmax4(s[0], s[1]), fmax4(s[2], s[3]));
        float tmx = fmaxf(fmaxf(mm[0], mm[1]), fmaxf(mm[2], mm[3]));
        tmx = fmaxf(tmx, __shfl_xor(tmx, 16));
        tmx = fmaxf(tmx, __shfl_xor(tmx, 32));
        bool upd = __any(tmx > mx + 8.0f);  // defer-max
        if (upd) {
          float mn = fmaxf(mx, tmx);
          float al = ex2(mx - mn);
          mx = mn;
          ls *= al;
          float alr[4];
#pragma unroll
          for (int r = 0; r < 4; r++) alr[r] = __shfl(al, hi * 4 + r);
#pragma unroll
          for (int nt = 0; nt < 4; nt++)
#pragma unroll
            for (int r = 0; r < 4; r++) ao[nt][r] *= alr[r];
        }
#pragma unroll
        for (int ct = 0; ct < 4; ct++)
#pragma unroll
          for (int r = 0; r < 4; r++) s[ct][r] = ex2(s[ct][r] - mx);
        f32x4 sm = s[0] + s[1] + s[2] + s[3];
        float rs = (sm[0] + sm[1]) + (sm[2] + sm[3]);
        rs += __shfl_xor(rs, 16);
        rs += __shfl_xor(rs, 32);
        ls += rs;

        // P -> per-wave LDS (row l15, XOR-swizzled, 8B writes)
#pragma unroll
        for (int ct = 0; ct < 4; ct++) {
          u32x2 pk = {cvt_pk_bf16(s[ct][0], s[ct][1]),
                      cvt_pk_bf16(s[ct][2], s[ct][3])};
          *(u32x2*)(&ldsPw[(l15 * 128 + ((ct * 32 + hi * 8) ^ psw)) >> 1]) = pk;
        }

        // PV (per-wave ldsP: no barrier, same-wave DS ordering)
        __builtin_amdgcn_s_setprio(1);
#pragma unroll
        for (int kk = 0; kk < 2; kk++) {
          bf16x8 pa = *(const bf16x8*)(&ldsPw[(l15 * 128 + ((kk * 64 + hi * 16) ^ psw)) >> 1]);
#pragma unroll
          for (int nt = 0; nt < 4; nt++) {
            int vrow = nt * 16 + l15;
            int c16 = (kk * 4 + hi) ^ (vrow & 7);
            bf16x8 vf = *(const bf16x8*)(&ldsV[cur][vrow * 64 + c16 * 8]);
            ao[nt] = mfma16(pa, vf, ao[nt]);
          }
        }
        __builtin_amdgcn_s_setprio(0);
      }
      __builtin_amdgcn_s_barrier();          // all waves done with buf cur
      if (kb + 2 < nkb) stage(cur, kb + 2);  // refill freed buffer
    }

    float lse = 0.69314718056f * mx + __logf(ls);  // back to natural log
    float ss = 1.f / (1.f + __expf(snk - lse));
    float f = ss / ls;
    float fr[4];
#pragma unroll
    for (int r = 0; r < 4; r++) fr[r] = __shfl(f, hi * 4 + r);
#pragma unroll
    for (int r = 0; r < 4; r++) {
      int row = q0 + hi * 4 + r;
#pragma unroll
      for (int nt = 0; nt < 4; nt++)
        Out[(size_t)row * (H * 64) + h * 64 + nt * 16 + l15] = f2bf(ao[nt][r] * fr[r]);
    }
  }
}

extern "C" void kernel_launch(void* const* d_in, const int* in_sizes, int n_in,
                              void* d_out, int out_size, void* d_ws, size_t ws_size,
                              hipStream_t stream) {
  const int S = 1536, HID = 2880, H = 64, HKV = 8;
  const int NQ = 4096, NKV = 512, NQKV = 5120, NPAD = 3072;

  const float* x     = (const float*)d_in[0];
  const float* rope  = (const float*)d_in[1];
  const float* wq_w  = (const float*)d_in[2];
  const float* wq_b  = (const float*)d_in[3];
  const float* wk_w  = (const float*)d_in[4];
  const float* wk_b  = (const float*)d_in[5];
  const float* wv_w  = (const float*)d_in[6];
  const float* wv_b  = (const float*)d_in[7];
  const float* wo_w  = (const float*)d_in[8];
  const float* wo_b  = (const float*)d_in[9];
  const float* sinks = (const float*)d_in[10];
  float* out = (float*)d_out;

  char* ws = (char*)d_ws;
  size_t off = 0;
  auto alloc = [&](size_t bytes) {
    char* p = ws + off;
    off = (off + bytes + 255) & ~(size_t)255;
    return p;
  };
  u16*   x_bf    = (u16*)  alloc((size_t)S * HID * 2);
  u16*   wqkv_bf = (u16*)  alloc((size_t)NQKV * HID * 2);
  u16*   wo_bf   = (u16*)  alloc((size_t)NPAD * NQ * 2);
  u16*   qkv_bf  = (u16*)  alloc((size_t)S * NQKV * 2);
  float* bias_p  = (float*)alloc((size_t)NQKV * 4);
  u16*   VTb     = (u16*)  alloc((size_t)HKV * 64 * S * 2);
  u16*   att     = (u16*)  alloc((size_t)S * NQ * 2);
  (void)ws_size; (void)n_in; (void)in_sizes; (void)out_size;

  auto cdiv = [](int a, int b) { return (a + b - 1) / b; };

  const int NCVT = (S * HID + NQ * HID + 2 * (NKV * HID) + NPAD * NQ + NQKV) / 8;
  cvt_all<<<cdiv(NCVT, 256), 256, 0, stream>>>(x, wq_w, wk_w, wv_w, wo_w,
                                               wq_b, wk_b, wv_b,
                                               x_bf, wqkv_bf, wo_bf, bias_p);

  // QKV projection + bias + RoPE + bf16 epilogue: grid 12 * 40 = 480 (%8==0)
  gemm128<1><<<(S / 128) * (NQKV / 128), 512, 0, stream>>>(
      x_bf, wqkv_bf, bias_p, nullptr, qkv_bf, rope, S, HID, NQKV, NQKV);

  cast_trT<<<dim3(S / 64, HKV), 256, 0, stream>>>(qkv_bf, VTb, S, HKV, NQKV, NQ + NKV);

  // 12 balanced q-pass pairs x 32 head-pairs = 384 uniform blocks
  attn_fwd<<<dim3(12, H / 2), 512, 0, stream>>>(qkv_bf, VTb, sinks, att, S, H, HKV);

  // wo projection: grid 12 * 24 = 288 (%8==0)
  gemm128<0><<<(S / 128) * (NPAD / 128), 512, 0, stream>>>(
      att, wo_bf, wo_b, out, nullptr, nullptr, S, NQ, HID, HID);
}